// Round 16
// baseline (175.515 us; speedup 1.0000x reference)
//
#include <hip/hip_runtime.h>
#include <hip/hip_fp16.h>
#include <math.h>

#define N_NODES 50000
#define N_EDGES 1600000
#define N_GRAPHS 512
#define HID 32
#define NEG_SLOPE 0.2f
#define SM_EPS 1e-16f
#define PAD 80          // max in-degree slots; dst~Poisson(32), P(deg>=80)*N ~ 5e-7
#define NBIN 511        // one bin per k_asm_gather block (ceil(50000/98))
#define BIN_W 98        // nodes per bin -> 98*80*4B = 31.4 KB LDS rows -> 2 blocks/CU
#define BIN_CAP 3800    // 3130 mean + ~12 sigma
#define EPT 10          // edges per thread in k_part_node
#define PART_BLOCKS 625 // 625*256*10 = 1,600,000 edges; 625*80 = 50,000 nodes
#define MAXG 8          // max graphs spanned by one 98-node bin (typ. 2)

// ---------------- kernel 1: fused edge partition + node transform ----------------
__global__ __launch_bounds__(256) void k_part_node(const int* __restrict__ ei,
                                                   const float* __restrict__ ea,
                                                   const float* __restrict__ W_edge,
                                                   const float* __restrict__ att_edge,
                                                   const float* __restrict__ x,
                                                   const float* __restrict__ W,
                                                   const float* __restrict__ att_src,
                                                   const float* __restrict__ att_dst,
                                                   uint2* __restrict__ part,
                                                   int* __restrict__ pcur,
                                                   __half2* __restrict__ h2,
                                                   float* __restrict__ a_src,
                                                   float* __restrict__ a_dst) {
    __shared__ float sv[3];
    __shared__ float sW[12 * 32], sas[32], sad[32];
    __shared__ int lcnt[NBIN], lcur[NBIN];
    int t = threadIdx.x;
    if (t < 3) {
        float v = 0.f;
        for (int j = 0; j < 32; ++j) v += W_edge[t * 32 + j] * att_edge[j];
        sv[t] = v;
    }
    for (int i = t; i < 12 * 32; i += 256) sW[i] = W[i];
    if (t < 32) { sas[t] = att_src[t]; sad[t] = att_dst[t]; }
    for (int i = t; i < NBIN; i += 256) lcnt[i] = 0;
    __syncthreads();

    // ---- phase A: edge partition (histogram -> global base -> ranked scatter) ----
    uint2 r[EPT];
    int bin[EPT];
    int ebase = blockIdx.x * (256 * EPT) + t;
#pragma unroll
    for (int i = 0; i < EPT; ++i) {
        int e = ebase + i * 256;
        int s = ei[e];
        int d = ei[N_EDGES + e];
        float aev = ea[e * 3 + 0] * sv[0] + ea[e * 3 + 1] * sv[1] + ea[e * 3 + 2] * sv[2];
        r[i] = make_uint2((unsigned)d | ((unsigned)s << 16), __float_as_uint(aev));
        bin[i] = d / BIN_W;
        atomicAdd(&lcnt[bin[i]], 1);
    }
    __syncthreads();
    for (int i = t; i < NBIN; i += 256) lcur[i] = atomicAdd(pcur + i, lcnt[i]);
    __syncthreads();
#pragma unroll
    for (int i = 0; i < EPT; ++i) {
        int pos = atomicAdd(&lcur[bin[i]], 1);
        if (pos < BIN_CAP) part[(size_t)bin[i] * BIN_CAP + pos] = r[i];
    }

    // ---- phase B: node transform, 80 nodes per block ----
    int n = blockIdx.x * 80 + t;
    if (t < 80 && n < N_NODES) {
        float xv[12];
#pragma unroll
        for (int j = 0; j < 12; ++j) xv[j] = x[n * 12 + j];
        float hv[32];
        float as = 0.f, ad = 0.f;
#pragma unroll
        for (int k = 0; k < 32; ++k) {
            float acc = 0.f;
#pragma unroll
            for (int j = 0; j < 12; ++j) acc += xv[j] * sW[j * 32 + k];
            hv[k] = acc;
            as += acc * sas[k];
            ad += acc * sad[k];
        }
        a_src[n] = as;
        a_dst[n] = ad;
        __half2 hp[16];
#pragma unroll
        for (int k = 0; k < 16; ++k) hp[k] = __floats2half2_rn(hv[2 * k], hv[2 * k + 1]);
        uint4* dst = (uint4*)(h2 + (size_t)n * 16);
        const uint4* srcp = (const uint4*)hp;
#pragma unroll
        for (int k = 0; k < 4; ++k) dst[k] = srcp[k];
    }
}

// ---------------- kernel 2: LDS assembly + paired exp pass + paired-FMA gather + pooling ----------------
__global__ __launch_bounds__(1024) void k_asm_gather(const uint2* __restrict__ part,
                                                     const int* __restrict__ pcur,
                                                     const __half2* __restrict__ h2,
                                                     const float* __restrict__ a_src,
                                                     const float* __restrict__ a_dst,
                                                     const float* __restrict__ bias,
                                                     const float* __restrict__ W_gate,
                                                     const float* __restrict__ b_gate,
                                                     const int* __restrict__ batch,
                                                     float* __restrict__ Sg,
                                                     float* __restrict__ gzg) {
    int b = blockIdx.x;
    int lo = b * BIN_W;
    if (lo >= N_NODES) return;
    int hi = lo + BIN_W; if (hi > N_NODES) hi = N_NODES;
    int nrow = hi - lo;
    __shared__ int lcur[BIN_W];
    __shared__ unsigned lbuck[BIN_W * PAD];   // 31.4 KB; rows 320B-aligned -> b64-safe
    __shared__ float el_row[BIN_W], zi_row[BIN_W], ad_row[BIN_W];
    __shared__ float S_local[MAXG][32];
    __shared__ float gz_local[MAXG];
    __shared__ int sgf, sgl;
    int t = threadIdx.x;
    if (t < BIN_W) { lcur[t] = 0; ad_row[t] = a_dst[lo + t]; }
    if (t < MAXG * 32) S_local[t >> 5][t & 31] = 0.f;
    if (t < MAXG) gz_local[t] = 0.f;
    if (t == 0) { sgf = batch[lo]; sgl = batch[hi - 1]; }
    __syncthreads();
    int gfirst = sgf;

    // ---- phase 1: assemble rows in LDS (own partition only, single read) ----
    int cnt = pcur[b]; if (cnt > BIN_CAP) cnt = BIN_CAP;
    const uint2* p = part + (size_t)b * BIN_CAP;
    for (int i = t; i < cnt; i += 1024) {
        uint2 r = p[i];
        int li = (int)(r.x & 0xFFFF) - lo;
        unsigned s = r.x >> 16;
        unsigned short hb = __half_as_ushort(__float2half_rn(__uint_as_float(r.y)));
        int pos = atomicAdd(&lcur[li], 1);
        if (pos < PAD) lbuck[li * PAD + pos] = s | ((unsigned)hb << 16);
    }
    __syncthreads();

    // ---- phase 1.5: wave-per-row, paired b64 entry access, exp once, shuffle-reduced ----
    {
        int l = t & 63, wl = t >> 6;
        for (int li = wl; li < nrow; li += 16) {
            int dc = lcur[li]; if (dc > PAD) dc = PAD;
            float adn = ad_row[li];
            float wpart = 0.f, aevpart = 0.f;
            int j0 = 2 * l;                       // 0..126 covers dc<=80 in ONE pass
            if (j0 < dc) {
                uint2 pr = *(const uint2*)(lbuck + li * PAD + j0);   // b64 read
                // entry j0
                {
                    int s = pr.x & 0xFFFF;
                    float aev = __half2float(__ushort_as_half((unsigned short)(pr.x >> 16)));
                    float a = a_src[s] + adn + aev;
                    a = a > 0.f ? a : NEG_SLOPE * a;
                    float w = __expf(a); w = w < 60000.f ? w : 60000.f;
                    unsigned short wh = __half_as_ushort(__float2half_rn(w));
                    pr.x = (unsigned)s | ((unsigned)wh << 16);
                    wpart += __half2float(__ushort_as_half(wh));
                    aevpart += aev;
                }
                // entry j0+1
                if (j0 + 1 < dc) {
                    int s = pr.y & 0xFFFF;
                    float aev = __half2float(__ushort_as_half((unsigned short)(pr.y >> 16)));
                    float a = a_src[s] + adn + aev;
                    a = a > 0.f ? a : NEG_SLOPE * a;
                    float w = __expf(a); w = w < 60000.f ? w : 60000.f;
                    unsigned short wh = __half_as_ushort(__float2half_rn(w));
                    pr.y = (unsigned)s | ((unsigned)wh << 16);
                    wpart += __half2float(__ushort_as_half(wh));
                    aevpart += aev;
                }
                *(uint2*)(lbuck + li * PAD + j0) = pr;               // b64 write-back
            }
#pragma unroll
            for (int m = 1; m <= 32; m <<= 1) {
                wpart += __shfl_xor(wpart, m);
                aevpart += __shfl_xor(aevpart, m);
            }
            if (l == 0) {
                int dg = lcur[li];
                float dgm = dg > 1 ? (float)dg : 1.f;
                float al = a_src[lo + li] + adn + aevpart / dgm;
                al = al > 0.f ? al : NEG_SLOPE * al;
                float el = __expf(al);
                el_row[li] = el;
                zi_row[li] = 1.f / (wpart + el + SM_EPS);
            }
        }
    }
    __syncthreads();

    // ---- phase 2: wave-per-node gather; lane es reads entry PAIR (2es,2es+1) via b64 ----
    int l = t & 63, wl = t >> 6;   // 16 waves
    int es = l >> 2;               // edge subgroup 0..15
    int cg = l & 3;                // channel group 0..3 (8 halves = one dwordx4)
    float bg0 = b_gate[0];

    for (int li = wl; li < nrow; li += 16) {
        int n = lo + li;
        int degc = lcur[li]; degc = degc < PAD ? degc : PAD;
        const unsigned* row = lbuck + li * PAD;

        float c0 = 0.f, c1 = 0.f, c2 = 0.f, c3 = 0.f, c4 = 0.f, c5 = 0.f, c6 = 0.f, c7 = 0.f;
        int j = 2 * es;                 // even, stride 32
        for (; j + 1 < degc; j += 32) {
            uint2 pr = *(const uint2*)(row + j);     // ds_read_b64: 2 edges
            int s0 = pr.x & 0xFFFF, s1 = pr.y & 0xFFFF;
            float w0 = __half2float(__ushort_as_half((unsigned short)(pr.x >> 16)));
            float w1 = __half2float(__ushort_as_half((unsigned short)(pr.y >> 16)));
            const uint4 u0 = *(const uint4*)(h2 + (size_t)s0 * 16 + cg * 4);
            const uint4 u1 = *(const uint4*)(h2 + (size_t)s1 * 16 + cg * 4);
            float2 f;
            f = __half22float2(*(const __half2*)&u0.x); c0 += w0 * f.x; c1 += w0 * f.y;
            f = __half22float2(*(const __half2*)&u0.y); c2 += w0 * f.x; c3 += w0 * f.y;
            f = __half22float2(*(const __half2*)&u0.z); c4 += w0 * f.x; c5 += w0 * f.y;
            f = __half22float2(*(const __half2*)&u0.w); c6 += w0 * f.x; c7 += w0 * f.y;
            f = __half22float2(*(const __half2*)&u1.x); c0 += w1 * f.x; c1 += w1 * f.y;
            f = __half22float2(*(const __half2*)&u1.y); c2 += w1 * f.x; c3 += w1 * f.y;
            f = __half22float2(*(const __half2*)&u1.z); c4 += w1 * f.x; c5 += w1 * f.y;
            f = __half22float2(*(const __half2*)&u1.w); c6 += w1 * f.x; c7 += w1 * f.y;
        }
        if (j < degc) {                 // odd tail: single entry at j == degc-1
            unsigned p0 = row[j];
            int s0 = p0 & 0xFFFF;
            float w0 = __half2float(__ushort_as_half((unsigned short)(p0 >> 16)));
            const uint4 u0 = *(const uint4*)(h2 + (size_t)s0 * 16 + cg * 4);
            float2 f;
            f = __half22float2(*(const __half2*)&u0.x); c0 += w0 * f.x; c1 += w0 * f.y;
            f = __half22float2(*(const __half2*)&u0.y); c2 += w0 * f.x; c3 += w0 * f.y;
            f = __half22float2(*(const __half2*)&u0.z); c4 += w0 * f.x; c5 += w0 * f.y;
            f = __half22float2(*(const __half2*)&u0.w); c6 += w0 * f.x; c7 += w0 * f.y;
        }

#pragma unroll
        for (int m = 4; m <= 32; m <<= 1) {
            c0 += __shfl_xor(c0, m); c1 += __shfl_xor(c1, m);
            c2 += __shfl_xor(c2, m); c3 += __shfl_xor(c3, m);
            c4 += __shfl_xor(c4, m); c5 += __shfl_xor(c5, m);
            c6 += __shfl_xor(c6, m); c7 += __shfl_xor(c7, m);
        }

        float el = el_row[li];
        float zi = zi_row[li];

        if (es == 0) {          // lanes 0..3, 8 channels each
            const uint4 un = *(const uint4*)(h2 + (size_t)n * 16 + cg * 4);
            float hn[8];
            float2 f;
            f = __half22float2(*(const __half2*)&un.x); hn[0] = f.x; hn[1] = f.y;
            f = __half22float2(*(const __half2*)&un.y); hn[2] = f.x; hn[3] = f.y;
            f = __half22float2(*(const __half2*)&un.z); hn[4] = f.x; hn[5] = f.y;
            f = __half22float2(*(const __half2*)&un.w); hn[6] = f.x; hn[7] = f.y;
            const float4 bva = *(const float4*)(bias + cg * 8);
            const float4 bvb = *(const float4*)(bias + cg * 8 + 4);
            float v[8];
            v[0] = (c0 + el * hn[0]) * zi + bva.x;
            v[1] = (c1 + el * hn[1]) * zi + bva.y;
            v[2] = (c2 + el * hn[2]) * zi + bva.z;
            v[3] = (c3 + el * hn[3]) * zi + bva.w;
            v[4] = (c4 + el * hn[4]) * zi + bvb.x;
            v[5] = (c5 + el * hn[5]) * zi + bvb.y;
            v[6] = (c6 + el * hn[6]) * zi + bvb.z;
            v[7] = (c7 + el * hn[7]) * zi + bvb.w;
#pragma unroll
            for (int k = 0; k < 8; ++k) v[k] = v[k] > 0.f ? v[k] : 0.f;   // relu
            const float4 wga = *(const float4*)(W_gate + cg * 8);
            const float4 wgb = *(const float4*)(W_gate + cg * 8 + 4);
            float g = v[0] * wga.x + v[1] * wga.y + v[2] * wga.z + v[3] * wga.w
                    + v[4] * wgb.x + v[5] * wgb.y + v[6] * wgb.z + v[7] * wgb.w;
            g += __shfl_xor(g, 1);
            g += __shfl_xor(g, 2);      // all 4 lanes hold the full gate dot
            float gen = __expf(g + bg0);
            int gi = batch[n] - gfirst; gi = gi < MAXG - 1 ? gi : MAXG - 1;
#pragma unroll
            for (int k = 0; k < 8; ++k) atomicAdd(&S_local[gi][cg * 8 + k], gen * v[k]);
            if (cg == 0) atomicAdd(&gz_local[gi], gen);
        }
    }
    __syncthreads();

    // ---- flush per-graph partials (33 atomics per graph spanned) ----
    int ngr = sgl - gfirst + 1; if (ngr > MAXG) ngr = MAXG;
    for (int i = t; i < ngr * 33; i += 1024) {
        int q = i / 33, c = i % 33;
        if (c < 32) atomicAdd(&Sg[(size_t)(gfirst + q) * 32 + c], S_local[q][c]);
        else atomicAdd(&gzg[gfirst + q], gz_local[q]);
    }
}

// ---------------- kernel 3: output head ----------------
__global__ __launch_bounds__(256) void k_out(const float* __restrict__ Sg,
                                             const float* __restrict__ gzg,
                                             const float* __restrict__ W_out,
                                             const float* __restrict__ b_out,
                                             float* __restrict__ out) {
    int g = blockIdx.x * blockDim.x + threadIdx.x;
    if (g >= N_GRAPHS) return;
    float zi = 1.f / (gzg[g] + SM_EPS);
    float acc = b_out[0];
#pragma unroll
    for (int k = 0; k < 32; ++k) acc += Sg[(size_t)g * 32 + k] * zi * W_out[k];
    out[g] = 1.f / (1.f + __expf(-acc));
}

extern "C" void kernel_launch(void* const* d_in, const int* in_sizes, int n_in,
                              void* d_out, int out_size, void* d_ws, size_t ws_size,
                              hipStream_t stream) {
    const float* x        = (const float*)d_in[0];
    const int*   ei       = (const int*)  d_in[1];
    const float* ea       = (const float*)d_in[2];
    const int*   batch    = (const int*)  d_in[3];
    const float* W        = (const float*)d_in[4];
    const float* att_src  = (const float*)d_in[5];
    const float* att_dst  = (const float*)d_in[6];
    const float* W_edge   = (const float*)d_in[7];
    const float* att_edge = (const float*)d_in[8];
    const float* bias     = (const float*)d_in[9];
    const float* W_gate   = (const float*)d_in[10];
    const float* b_gate   = (const float*)d_in[11];
    const float* W_out    = (const float*)d_in[12];
    const float* b_out    = (const float*)d_in[13];
    float* out = (float*)d_out;

    // workspace layout
    char* wsb = (char*)d_ws;
    uint2*    part_  = (uint2*)wsb;                                // NBIN*BIN_CAP uint2 = 15.5 MB
    __half2*  h2     = (__half2*)(part_ + (size_t)NBIN * BIN_CAP); // 16N half2 = 3.2 MB
    float*    a_src  = (float*)(h2 + (size_t)16 * N_NODES);        // N
    float*    a_dst  = a_src + N_NODES;                            // N
    // ---- zeroed region (contiguous: Sg, gzg, pcur) ----
    float*    Sg     = a_dst + N_NODES;                            // G*32
    float*    gzg    = Sg + (size_t)N_GRAPHS * 32;                 // G
    int*      pcur   = (int*)(gzg + N_GRAPHS);                     // NBIN

    size_t zero_bytes = ((size_t)N_GRAPHS * 33 + NBIN) * sizeof(float);
    hipMemsetAsync(Sg, 0, zero_bytes, stream);

    const int B = 256;
    k_part_node<<<PART_BLOCKS, B, 0, stream>>>(ei, ea, W_edge, att_edge, x, W, att_src,
                                               att_dst, part_, pcur, h2, a_src, a_dst);
    k_asm_gather<<<NBIN, 1024, 0, stream>>>(part_, pcur, h2, a_src, a_dst, bias,
                                            W_gate, b_gate, batch, Sg, gzg);
    k_out<<<(N_GRAPHS + B - 1) / B, B, 0, stream>>>(Sg, gzg, W_out, b_out, out);
}

// Round 17
// 169.704 us; speedup vs baseline: 1.0342x; 1.0342x over previous
//
#include <hip/hip_runtime.h>
#include <hip/hip_fp16.h>
#include <math.h>

#define N_NODES 50000
#define N_EDGES 1600000
#define N_GRAPHS 512
#define HID 32
#define NEG_SLOPE 0.2f
#define SM_EPS 1e-16f
#define PAD 80          // max in-degree slots; dst~Poisson(32), P(deg>=80)*N ~ 5e-7
#define NBIN 511        // one bin per k_asm_gather block (ceil(50000/98))
#define BIN_W 98        // nodes per bin -> 98*80*4B = 31.4 KB LDS rows -> 2 blocks/CU
#define BIN_CAP 3800    // 3130 mean + ~12 sigma
#define EPT 10          // edges per thread in k_part_node
#define PART_BLOCKS 313 // 313*512*10 = 1,602,560 >= 1.6M edges; 313*160 = 50,080 nodes

// ---------------- kernel 1: fused edge partition + node transform (512-thread blocks) ----------------
// 5120 edges/block -> ~10-entry runs per bin (80 B) -> halved scattered-write transactions.
__global__ __launch_bounds__(512) void k_part_node(const int* __restrict__ ei,
                                                   const float* __restrict__ ea,
                                                   const float* __restrict__ W_edge,
                                                   const float* __restrict__ att_edge,
                                                   const float* __restrict__ x,
                                                   const float* __restrict__ W,
                                                   const float* __restrict__ att_src,
                                                   const float* __restrict__ att_dst,
                                                   uint2* __restrict__ part,
                                                   int* __restrict__ pcur,
                                                   __half2* __restrict__ h2,
                                                   float* __restrict__ a_src,
                                                   float* __restrict__ a_dst) {
    __shared__ float sv[3];
    __shared__ float sW[12 * 32], sas[32], sad[32];
    __shared__ int lcnt[NBIN], lcur[NBIN];
    int t = threadIdx.x;
    if (t < 3) {
        float v = 0.f;
        for (int j = 0; j < 32; ++j) v += W_edge[t * 32 + j] * att_edge[j];
        sv[t] = v;
    }
    for (int i = t; i < 12 * 32; i += 512) sW[i] = W[i];
    if (t < 32) { sas[t] = att_src[t]; sad[t] = att_dst[t]; }
    for (int i = t; i < NBIN; i += 512) lcnt[i] = 0;
    __syncthreads();

    // ---- phase A: edge partition (histogram -> global base -> ranked scatter) ----
    uint2 r[EPT];
    int bin[EPT];
    int ebase = blockIdx.x * (512 * EPT) + t;
#pragma unroll
    for (int i = 0; i < EPT; ++i) {
        int e = ebase + i * 512;
        if (e < N_EDGES) {
            int s = ei[e];
            int d = ei[N_EDGES + e];
            float aev = ea[e * 3 + 0] * sv[0] + ea[e * 3 + 1] * sv[1] + ea[e * 3 + 2] * sv[2];
            r[i] = make_uint2((unsigned)d | ((unsigned)s << 16), __float_as_uint(aev));
            bin[i] = d / BIN_W;
            atomicAdd(&lcnt[bin[i]], 1);
        } else {
            bin[i] = -1;
        }
    }
    __syncthreads();
    for (int i = t; i < NBIN; i += 512) lcur[i] = atomicAdd(pcur + i, lcnt[i]);
    __syncthreads();
#pragma unroll
    for (int i = 0; i < EPT; ++i) {
        if (bin[i] >= 0) {
            int pos = atomicAdd(&lcur[bin[i]], 1);
            if (pos < BIN_CAP) part[(size_t)bin[i] * BIN_CAP + pos] = r[i];
        }
    }

    // ---- phase B: node transform, 160 nodes per block ----
    int n = blockIdx.x * 160 + t;
    if (t < 160 && n < N_NODES) {
        float xv[12];
#pragma unroll
        for (int j = 0; j < 12; ++j) xv[j] = x[n * 12 + j];
        float hv[32];
        float as = 0.f, ad = 0.f;
#pragma unroll
        for (int k = 0; k < 32; ++k) {
            float acc = 0.f;
#pragma unroll
            for (int j = 0; j < 12; ++j) acc += xv[j] * sW[j * 32 + k];
            hv[k] = acc;
            as += acc * sas[k];
            ad += acc * sad[k];
        }
        a_src[n] = as;
        a_dst[n] = ad;
        __half2 hp[16];
#pragma unroll
        for (int k = 0; k < 16; ++k) hp[k] = __floats2half2_rn(hv[2 * k], hv[2 * k + 1]);
        uint4* dst = (uint4*)(h2 + (size_t)n * 16);
        const uint4* srcp = (const uint4*)hp;
#pragma unroll
        for (int k = 0; k < 4; ++k) dst[k] = srcp[k];
    }
}

// ---------------- kernel 2: LDS assembly + wave-per-row exp pass + FMA gather + pooling ----------------
// (phase 2 = R15's proven b32 form; R16's b64 pairing regressed — latency-bound, not issue-bound)
#define MAXG 8
__global__ __launch_bounds__(1024) void k_asm_gather(const uint2* __restrict__ part,
                                                     const int* __restrict__ pcur,
                                                     const __half2* __restrict__ h2,
                                                     const float* __restrict__ a_src,
                                                     const float* __restrict__ a_dst,
                                                     const float* __restrict__ bias,
                                                     const float* __restrict__ W_gate,
                                                     const float* __restrict__ b_gate,
                                                     const int* __restrict__ batch,
                                                     float* __restrict__ Sg,
                                                     float* __restrict__ gzg) {
    int b = blockIdx.x;
    int lo = b * BIN_W;
    if (lo >= N_NODES) return;
    int hi = lo + BIN_W; if (hi > N_NODES) hi = N_NODES;
    int nrow = hi - lo;
    __shared__ int lcur[BIN_W];
    __shared__ unsigned lbuck[BIN_W * PAD];   // 31.4 KB
    __shared__ float el_row[BIN_W], zi_row[BIN_W], ad_row[BIN_W];
    __shared__ float S_local[MAXG][32];
    __shared__ float gz_local[MAXG];
    __shared__ int sgf, sgl;
    int t = threadIdx.x;
    if (t < BIN_W) { lcur[t] = 0; ad_row[t] = a_dst[lo + t]; }
    if (t < MAXG * 32) S_local[t >> 5][t & 31] = 0.f;
    if (t < MAXG) gz_local[t] = 0.f;
    if (t == 0) { sgf = batch[lo]; sgl = batch[hi - 1]; }
    __syncthreads();
    int gfirst = sgf;

    // ---- phase 1: assemble rows in LDS (own partition only, single read) ----
    int cnt = pcur[b]; if (cnt > BIN_CAP) cnt = BIN_CAP;
    const uint2* p = part + (size_t)b * BIN_CAP;
    for (int i = t; i < cnt; i += 1024) {
        uint2 r = p[i];
        int li = (int)(r.x & 0xFFFF) - lo;
        unsigned s = r.x >> 16;
        unsigned short hb = __half_as_ushort(__float2half_rn(__uint_as_float(r.y)));
        int pos = atomicAdd(&lcur[li], 1);
        if (pos < PAD) lbuck[li * PAD + pos] = s | ((unsigned)hb << 16);
    }
    __syncthreads();

    // ---- phase 1.5: wave-per-row, exp ONCE per edge, shuffle-reduced (no LDS atomics) ----
    {
        int l = t & 63, wl = t >> 6;
        for (int li = wl; li < nrow; li += 16) {
            int dc = lcur[li]; if (dc > PAD) dc = PAD;
            float adn = ad_row[li];
            float wpart = 0.f, aevpart = 0.f;
            for (int j = l; j < dc; j += 64) {   // <=2 iterations (dc<=80)
                unsigned e = lbuck[li * PAD + j];
                int s = e & 0xFFFF;
                float aev = __half2float(__ushort_as_half((unsigned short)(e >> 16)));
                float a = a_src[s] + adn + aev;
                a = a > 0.f ? a : NEG_SLOPE * a;
                float w = __expf(a);
                w = w < 60000.f ? w : 60000.f;   // half-range guard
                unsigned short wh = __half_as_ushort(__float2half_rn(w));
                lbuck[li * PAD + j] = (unsigned)s | ((unsigned)wh << 16);
                wpart += __half2float(__ushort_as_half(wh));
                aevpart += aev;
            }
#pragma unroll
            for (int m = 1; m <= 32; m <<= 1) {
                wpart += __shfl_xor(wpart, m);
                aevpart += __shfl_xor(aevpart, m);
            }
            if (l == 0) {
                int dg = lcur[li];
                float dgm = dg > 1 ? (float)dg : 1.f;
                float al = a_src[lo + li] + adn + aevpart / dgm;
                al = al > 0.f ? al : NEG_SLOPE * al;
                float el = __expf(al);
                el_row[li] = el;
                zi_row[li] = 1.f / (wpart + el + SM_EPS);
            }
        }
    }
    __syncthreads();

    // ---- phase 2: wave-per-node FMA-only gather, pool into LDS ----
    int l = t & 63, wl = t >> 6;   // 16 waves
    int es = l >> 2;               // edge subgroup 0..15
    int cg = l & 3;                // channel group 0..3 (8 halves = one dwordx4)
    float bg0 = b_gate[0];

    for (int li = wl; li < nrow; li += 16) {
        int n = lo + li;
        int degc = lcur[li]; degc = degc < PAD ? degc : PAD;
        const unsigned* row = lbuck + li * PAD;

        float c0 = 0.f, c1 = 0.f, c2 = 0.f, c3 = 0.f, c4 = 0.f, c5 = 0.f, c6 = 0.f, c7 = 0.f;
        int j = es;
        for (; j + 16 < degc; j += 32) {
            unsigned p0 = row[j], p1 = row[j + 16];
            int s0 = p0 & 0xFFFF, s1 = p1 & 0xFFFF;
            float w0 = __half2float(__ushort_as_half((unsigned short)(p0 >> 16)));
            float w1 = __half2float(__ushort_as_half((unsigned short)(p1 >> 16)));
            const uint4 u0 = *(const uint4*)(h2 + (size_t)s0 * 16 + cg * 4);
            const uint4 u1 = *(const uint4*)(h2 + (size_t)s1 * 16 + cg * 4);
            float2 f;
            f = __half22float2(*(const __half2*)&u0.x); c0 += w0 * f.x; c1 += w0 * f.y;
            f = __half22float2(*(const __half2*)&u0.y); c2 += w0 * f.x; c3 += w0 * f.y;
            f = __half22float2(*(const __half2*)&u0.z); c4 += w0 * f.x; c5 += w0 * f.y;
            f = __half22float2(*(const __half2*)&u0.w); c6 += w0 * f.x; c7 += w0 * f.y;
            f = __half22float2(*(const __half2*)&u1.x); c0 += w1 * f.x; c1 += w1 * f.y;
            f = __half22float2(*(const __half2*)&u1.y); c2 += w1 * f.x; c3 += w1 * f.y;
            f = __half22float2(*(const __half2*)&u1.z); c4 += w1 * f.x; c5 += w1 * f.y;
            f = __half22float2(*(const __half2*)&u1.w); c6 += w1 * f.x; c7 += w1 * f.y;
        }
        if (j < degc) {
            unsigned p0 = row[j];
            int s0 = p0 & 0xFFFF;
            float w0 = __half2float(__ushort_as_half((unsigned short)(p0 >> 16)));
            const uint4 u0 = *(const uint4*)(h2 + (size_t)s0 * 16 + cg * 4);
            float2 f;
            f = __half22float2(*(const __half2*)&u0.x); c0 += w0 * f.x; c1 += w0 * f.y;
            f = __half22float2(*(const __half2*)&u0.y); c2 += w0 * f.x; c3 += w0 * f.y;
            f = __half22float2(*(const __half2*)&u0.z); c4 += w0 * f.x; c5 += w0 * f.y;
            f = __half22float2(*(const __half2*)&u0.w); c6 += w0 * f.x; c7 += w0 * f.y;
        }

#pragma unroll
        for (int m = 4; m <= 32; m <<= 1) {
            c0 += __shfl_xor(c0, m); c1 += __shfl_xor(c1, m);
            c2 += __shfl_xor(c2, m); c3 += __shfl_xor(c3, m);
            c4 += __shfl_xor(c4, m); c5 += __shfl_xor(c5, m);
            c6 += __shfl_xor(c6, m); c7 += __shfl_xor(c7, m);
        }

        float el = el_row[li];
        float zi = zi_row[li];

        if (es == 0) {          // lanes 0..3, 8 channels each
            const uint4 un = *(const uint4*)(h2 + (size_t)n * 16 + cg * 4);
            float hn[8];
            float2 f;
            f = __half22float2(*(const __half2*)&un.x); hn[0] = f.x; hn[1] = f.y;
            f = __half22float2(*(const __half2*)&un.y); hn[2] = f.x; hn[3] = f.y;
            f = __half22float2(*(const __half2*)&un.z); hn[4] = f.x; hn[5] = f.y;
            f = __half22float2(*(const __half2*)&un.w); hn[6] = f.x; hn[7] = f.y;
            const float4 bva = *(const float4*)(bias + cg * 8);
            const float4 bvb = *(const float4*)(bias + cg * 8 + 4);
            float v[8];
            v[0] = (c0 + el * hn[0]) * zi + bva.x;
            v[1] = (c1 + el * hn[1]) * zi + bva.y;
            v[2] = (c2 + el * hn[2]) * zi + bva.z;
            v[3] = (c3 + el * hn[3]) * zi + bva.w;
            v[4] = (c4 + el * hn[4]) * zi + bvb.x;
            v[5] = (c5 + el * hn[5]) * zi + bvb.y;
            v[6] = (c6 + el * hn[6]) * zi + bvb.z;
            v[7] = (c7 + el * hn[7]) * zi + bvb.w;
#pragma unroll
            for (int k = 0; k < 8; ++k) v[k] = v[k] > 0.f ? v[k] : 0.f;   // relu
            const float4 wga = *(const float4*)(W_gate + cg * 8);
            const float4 wgb = *(const float4*)(W_gate + cg * 8 + 4);
            float g = v[0] * wga.x + v[1] * wga.y + v[2] * wga.z + v[3] * wga.w
                    + v[4] * wgb.x + v[5] * wgb.y + v[6] * wgb.z + v[7] * wgb.w;
            g += __shfl_xor(g, 1);
            g += __shfl_xor(g, 2);      // all 4 lanes hold the full gate dot
            float gen = __expf(g + bg0);
            int gi = batch[n] - gfirst; gi = gi < MAXG - 1 ? gi : MAXG - 1;
#pragma unroll
            for (int k = 0; k < 8; ++k) atomicAdd(&S_local[gi][cg * 8 + k], gen * v[k]);
            if (cg == 0) atomicAdd(&gz_local[gi], gen);
        }
    }
    __syncthreads();

    // ---- flush per-graph partials (33 atomics per graph spanned) ----
    int ngr = sgl - gfirst + 1; if (ngr > MAXG) ngr = MAXG;
    for (int i = t; i < ngr * 33; i += 1024) {
        int q = i / 33, c = i % 33;
        if (c < 32) atomicAdd(&Sg[(size_t)(gfirst + q) * 32 + c], S_local[q][c]);
        else atomicAdd(&gzg[gfirst + q], gz_local[q]);
    }
}

// ---------------- kernel 3: output head ----------------
__global__ __launch_bounds__(256) void k_out(const float* __restrict__ Sg,
                                             const float* __restrict__ gzg,
                                             const float* __restrict__ W_out,
                                             const float* __restrict__ b_out,
                                             float* __restrict__ out) {
    int g = blockIdx.x * blockDim.x + threadIdx.x;
    if (g >= N_GRAPHS) return;
    float zi = 1.f / (gzg[g] + SM_EPS);
    float acc = b_out[0];
#pragma unroll
    for (int k = 0; k < 32; ++k) acc += Sg[(size_t)g * 32 + k] * zi * W_out[k];
    out[g] = 1.f / (1.f + __expf(-acc));
}

extern "C" void kernel_launch(void* const* d_in, const int* in_sizes, int n_in,
                              void* d_out, int out_size, void* d_ws, size_t ws_size,
                              hipStream_t stream) {
    const float* x        = (const float*)d_in[0];
    const int*   ei       = (const int*)  d_in[1];
    const float* ea       = (const float*)d_in[2];
    const int*   batch    = (const int*)  d_in[3];
    const float* W        = (const float*)d_in[4];
    const float* att_src  = (const float*)d_in[5];
    const float* att_dst  = (const float*)d_in[6];
    const float* W_edge   = (const float*)d_in[7];
    const float* att_edge = (const float*)d_in[8];
    const float* bias     = (const float*)d_in[9];
    const float* W_gate   = (const float*)d_in[10];
    const float* b_gate   = (const float*)d_in[11];
    const float* W_out    = (const float*)d_in[12];
    const float* b_out    = (const float*)d_in[13];
    float* out = (float*)d_out;

    // workspace layout
    char* wsb = (char*)d_ws;
    uint2*    part_  = (uint2*)wsb;                                // NBIN*BIN_CAP uint2 = 15.5 MB
    __half2*  h2     = (__half2*)(part_ + (size_t)NBIN * BIN_CAP); // 16N half2 = 3.2 MB
    float*    a_src  = (float*)(h2 + (size_t)16 * N_NODES);        // N
    float*    a_dst  = a_src + N_NODES;                            // N
    // ---- zeroed region (contiguous: Sg, gzg, pcur) ----
    float*    Sg     = a_dst + N_NODES;                            // G*32
    float*    gzg    = Sg + (size_t)N_GRAPHS * 32;                 // G
    int*      pcur   = (int*)(gzg + N_GRAPHS);                     // NBIN

    size_t zero_bytes = ((size_t)N_GRAPHS * 33 + NBIN) * sizeof(float);
    hipMemsetAsync(Sg, 0, zero_bytes, stream);

    k_part_node<<<PART_BLOCKS, 512, 0, stream>>>(ei, ea, W_edge, att_edge, x, W, att_src,
                                                 att_dst, part_, pcur, h2, a_src, a_dst);
    k_asm_gather<<<NBIN, 1024, 0, stream>>>(part_, pcur, h2, a_src, a_dst, bias,
                                            W_gate, b_gate, batch, Sg, gzg);
    k_out<<<(N_GRAPHS + 255) / 256, 256, 0, stream>>>(Sg, gzg, W_out, b_out, out);
}

// Round 18
// 167.690 us; speedup vs baseline: 1.0467x; 1.0120x over previous
//
#include <hip/hip_runtime.h>
#include <hip/hip_fp16.h>
#include <math.h>

#define N_NODES 50000
#define N_EDGES 1600000
#define N_GRAPHS 512
#define HID 32
#define NEG_SLOPE 0.2f
#define SM_EPS 1e-16f
#define PAD 80          // max in-degree slots; dst~Poisson(32), P(deg>=80)*N ~ 5e-7
#define NBIN 511        // one bin per k_asm_gather block (ceil(50000/98))
#define BIN_W 98        // nodes per bin -> 98*80*4B = 31.4 KB LDS rows -> 2 blocks/CU
#define BIN_CAP 3800    // 3130 mean + ~12 sigma
#define EPT 10          // edges per thread in k_part_node
#define PART_BLOCKS 313 // 313*512*10 = 1,602,560 >= 1.6M edges; 313*160 = 50,080 nodes
#define MAXG 8          // max graphs spanned by one 98-node bin (typ. 2)

// ---------------- kernel 1: fused edge partition + node transform (512 threads, R17 form) ----------------
__global__ __launch_bounds__(512) void k_part_node(const int* __restrict__ ei,
                                                   const float* __restrict__ ea,
                                                   const float* __restrict__ W_edge,
                                                   const float* __restrict__ att_edge,
                                                   const float* __restrict__ x,
                                                   const float* __restrict__ W,
                                                   const float* __restrict__ att_src,
                                                   const float* __restrict__ att_dst,
                                                   uint2* __restrict__ part,
                                                   int* __restrict__ pcur,
                                                   __half2* __restrict__ h2,
                                                   float* __restrict__ a_src,
                                                   float* __restrict__ a_dst) {
    __shared__ float sv[3];
    __shared__ float sW[12 * 32], sas[32], sad[32];
    __shared__ int lcnt[NBIN], lcur[NBIN];
    int t = threadIdx.x;
    if (t < 3) {
        float v = 0.f;
        for (int j = 0; j < 32; ++j) v += W_edge[t * 32 + j] * att_edge[j];
        sv[t] = v;
    }
    for (int i = t; i < 12 * 32; i += 512) sW[i] = W[i];
    if (t < 32) { sas[t] = att_src[t]; sad[t] = att_dst[t]; }
    for (int i = t; i < NBIN; i += 512) lcnt[i] = 0;
    __syncthreads();

    // ---- phase A: edge partition (histogram -> global base -> ranked scatter) ----
    uint2 r[EPT];
    int bin[EPT];
    int ebase = blockIdx.x * (512 * EPT) + t;
#pragma unroll
    for (int i = 0; i < EPT; ++i) {
        int e = ebase + i * 512;
        if (e < N_EDGES) {
            int s = ei[e];
            int d = ei[N_EDGES + e];
            float aev = ea[e * 3 + 0] * sv[0] + ea[e * 3 + 1] * sv[1] + ea[e * 3 + 2] * sv[2];
            r[i] = make_uint2((unsigned)d | ((unsigned)s << 16), __float_as_uint(aev));
            bin[i] = d / BIN_W;
            atomicAdd(&lcnt[bin[i]], 1);
        } else {
            bin[i] = -1;
        }
    }
    __syncthreads();
    for (int i = t; i < NBIN; i += 512) lcur[i] = atomicAdd(pcur + i, lcnt[i]);
    __syncthreads();
#pragma unroll
    for (int i = 0; i < EPT; ++i) {
        if (bin[i] >= 0) {
            int pos = atomicAdd(&lcur[bin[i]], 1);
            if (pos < BIN_CAP) part[(size_t)bin[i] * BIN_CAP + pos] = r[i];
        }
    }

    // ---- phase B: node transform, 160 nodes per block ----
    int n = blockIdx.x * 160 + t;
    if (t < 160 && n < N_NODES) {
        float xv[12];
#pragma unroll
        for (int j = 0; j < 12; ++j) xv[j] = x[n * 12 + j];
        float hv[32];
        float as = 0.f, ad = 0.f;
#pragma unroll
        for (int k = 0; k < 32; ++k) {
            float acc = 0.f;
#pragma unroll
            for (int j = 0; j < 12; ++j) acc += xv[j] * sW[j * 32 + k];
            hv[k] = acc;
            as += acc * sas[k];
            ad += acc * sad[k];
        }
        a_src[n] = as;
        a_dst[n] = ad;
        __half2 hp[16];
#pragma unroll
        for (int k = 0; k < 16; ++k) hp[k] = __floats2half2_rn(hv[2 * k], hv[2 * k + 1]);
        uint4* dst = (uint4*)(h2 + (size_t)n * 16);
        const uint4* srcp = (const uint4*)hp;
#pragma unroll
        for (int k = 0; k < 4; ++k) dst[k] = srcp[k];
    }
}

// ---------------- kernel 2: LDS assembly + gather + fused pooling (R13 form — fastest measured) ----------------
__global__ __launch_bounds__(1024) void k_asm_gather(const uint2* __restrict__ part,
                                                     const int* __restrict__ pcur,
                                                     const __half2* __restrict__ h2,
                                                     const float* __restrict__ a_src,
                                                     const float* __restrict__ a_dst,
                                                     const float* __restrict__ bias,
                                                     const float* __restrict__ W_gate,
                                                     const float* __restrict__ b_gate,
                                                     const int* __restrict__ batch,
                                                     float* __restrict__ Sg,
                                                     float* __restrict__ gzg) {
    int b = blockIdx.x;
    int lo = b * BIN_W;
    if (lo >= N_NODES) return;
    int hi = lo + BIN_W; if (hi > N_NODES) hi = N_NODES;
    int nrow = hi - lo;
    __shared__ int lcur[BIN_W];
    __shared__ unsigned lbuck[BIN_W * PAD];   // 31.4 KB
    __shared__ float S_local[MAXG][32];
    __shared__ float gz_local[MAXG];
    __shared__ int sgf, sgl;
    int t = threadIdx.x;
    if (t < BIN_W) lcur[t] = 0;
    if (t < MAXG * 32) S_local[t >> 5][t & 31] = 0.f;
    if (t < MAXG) gz_local[t] = 0.f;
    if (t == 0) { sgf = batch[lo]; sgl = batch[hi - 1]; }
    __syncthreads();
    int gfirst = sgf;

    // ---- phase 1: assemble rows in LDS (own partition only, single read) ----
    int cnt = pcur[b]; if (cnt > BIN_CAP) cnt = BIN_CAP;
    const uint2* p = part + (size_t)b * BIN_CAP;
    for (int i = t; i < cnt; i += 1024) {
        uint2 r = p[i];
        int li = (int)(r.x & 0xFFFF) - lo;
        unsigned s = r.x >> 16;
        unsigned short hb = __half_as_ushort(__float2half_rn(__uint_as_float(r.y)));
        int pos = atomicAdd(&lcur[li], 1);
        if (pos < PAD) lbuck[li * PAD + pos] = s | ((unsigned)hb << 16);
    }
    __syncthreads();

    // ---- phase 2: wave-per-node gather (inline exp, R13 form), pool into LDS ----
    int l = t & 63, wl = t >> 6;   // 16 waves
    int es = l >> 2;               // edge subgroup 0..15
    int cg = l & 3;                // channel group 0..3 (8 halves = one dwordx4)
    float bg0 = b_gate[0];

    for (int li = wl; li < nrow; li += 16) {
        int n = lo + li;
        int deg_full = lcur[li];
        int degc = deg_full < PAD ? deg_full : PAD;
        float adst_n = a_dst[n];
        const unsigned* row = lbuck + li * PAD;

        float c0 = 0.f, c1 = 0.f, c2 = 0.f, c3 = 0.f, c4 = 0.f, c5 = 0.f, c6 = 0.f, c7 = 0.f;
        float wsum = 0.f, aevsum = 0.f;
        int j = es;
        for (; j + 16 < degc; j += 32) {
            unsigned p0 = row[j], p1 = row[j + 16];
            int s0 = p0 & 0xFFFF, s1 = p1 & 0xFFFF;
            float aev0 = __half2float(__ushort_as_half((unsigned short)(p0 >> 16)));
            float aev1 = __half2float(__ushort_as_half((unsigned short)(p1 >> 16)));
            float as0 = a_src[s0], as1 = a_src[s1];
            const uint4 u0 = *(const uint4*)(h2 + (size_t)s0 * 16 + cg * 4);
            const uint4 u1 = *(const uint4*)(h2 + (size_t)s1 * 16 + cg * 4);
            float a0 = as0 + adst_n + aev0; a0 = a0 > 0.f ? a0 : NEG_SLOPE * a0;
            float a1 = as1 + adst_n + aev1; a1 = a1 > 0.f ? a1 : NEG_SLOPE * a1;
            float w0 = __expf(a0), w1 = __expf(a1);
            wsum += w0 + w1; aevsum += aev0 + aev1;
            float2 f;
            f = __half22float2(*(const __half2*)&u0.x); c0 += w0 * f.x; c1 += w0 * f.y;
            f = __half22float2(*(const __half2*)&u0.y); c2 += w0 * f.x; c3 += w0 * f.y;
            f = __half22float2(*(const __half2*)&u0.z); c4 += w0 * f.x; c5 += w0 * f.y;
            f = __half22float2(*(const __half2*)&u0.w); c6 += w0 * f.x; c7 += w0 * f.y;
            f = __half22float2(*(const __half2*)&u1.x); c0 += w1 * f.x; c1 += w1 * f.y;
            f = __half22float2(*(const __half2*)&u1.y); c2 += w1 * f.x; c3 += w1 * f.y;
            f = __half22float2(*(const __half2*)&u1.z); c4 += w1 * f.x; c5 += w1 * f.y;
            f = __half22float2(*(const __half2*)&u1.w); c6 += w1 * f.x; c7 += w1 * f.y;
        }
        if (j < degc) {
            unsigned p0 = row[j];
            int s0 = p0 & 0xFFFF;
            float aev0 = __half2float(__ushort_as_half((unsigned short)(p0 >> 16)));
            float a0 = a_src[s0] + adst_n + aev0; a0 = a0 > 0.f ? a0 : NEG_SLOPE * a0;
            float w0 = __expf(a0);
            const uint4 u0 = *(const uint4*)(h2 + (size_t)s0 * 16 + cg * 4);
            wsum += w0; aevsum += aev0;
            float2 f;
            f = __half22float2(*(const __half2*)&u0.x); c0 += w0 * f.x; c1 += w0 * f.y;
            f = __half22float2(*(const __half2*)&u0.y); c2 += w0 * f.x; c3 += w0 * f.y;
            f = __half22float2(*(const __half2*)&u0.z); c4 += w0 * f.x; c5 += w0 * f.y;
            f = __half22float2(*(const __half2*)&u0.w); c6 += w0 * f.x; c7 += w0 * f.y;
        }

#pragma unroll
        for (int m = 4; m <= 32; m <<= 1) {
            c0 += __shfl_xor(c0, m); c1 += __shfl_xor(c1, m);
            c2 += __shfl_xor(c2, m); c3 += __shfl_xor(c3, m);
            c4 += __shfl_xor(c4, m); c5 += __shfl_xor(c5, m);
            c6 += __shfl_xor(c6, m); c7 += __shfl_xor(c7, m);
            wsum += __shfl_xor(wsum, m); aevsum += __shfl_xor(aevsum, m);
        }

        float dgm = deg_full > 1 ? (float)deg_full : 1.f;
        float al = a_src[n] + adst_n + aevsum / dgm;
        al = al > 0.f ? al : NEG_SLOPE * al;
        float el = __expf(al);
        float zi = 1.f / (wsum + el + SM_EPS);

        if (es == 0) {          // lanes 0..3, 8 channels each
            const uint4 un = *(const uint4*)(h2 + (size_t)n * 16 + cg * 4);
            float hn[8];
            float2 f;
            f = __half22float2(*(const __half2*)&un.x); hn[0] = f.x; hn[1] = f.y;
            f = __half22float2(*(const __half2*)&un.y); hn[2] = f.x; hn[3] = f.y;
            f = __half22float2(*(const __half2*)&un.z); hn[4] = f.x; hn[5] = f.y;
            f = __half22float2(*(const __half2*)&un.w); hn[6] = f.x; hn[7] = f.y;
            const float4 bva = *(const float4*)(bias + cg * 8);
            const float4 bvb = *(const float4*)(bias + cg * 8 + 4);
            float v[8];
            v[0] = (c0 + el * hn[0]) * zi + bva.x;
            v[1] = (c1 + el * hn[1]) * zi + bva.y;
            v[2] = (c2 + el * hn[2]) * zi + bva.z;
            v[3] = (c3 + el * hn[3]) * zi + bva.w;
            v[4] = (c4 + el * hn[4]) * zi + bvb.x;
            v[5] = (c5 + el * hn[5]) * zi + bvb.y;
            v[6] = (c6 + el * hn[6]) * zi + bvb.z;
            v[7] = (c7 + el * hn[7]) * zi + bvb.w;
#pragma unroll
            for (int k = 0; k < 8; ++k) v[k] = v[k] > 0.f ? v[k] : 0.f;   // relu
            const float4 wga = *(const float4*)(W_gate + cg * 8);
            const float4 wgb = *(const float4*)(W_gate + cg * 8 + 4);
            float g = v[0] * wga.x + v[1] * wga.y + v[2] * wga.z + v[3] * wga.w
                    + v[4] * wgb.x + v[5] * wgb.y + v[6] * wgb.z + v[7] * wgb.w;
            g += __shfl_xor(g, 1);
            g += __shfl_xor(g, 2);      // all 4 lanes hold the full gate dot
            float gen = __expf(g + bg0);
            int gi = batch[n] - gfirst; gi = gi < MAXG - 1 ? gi : MAXG - 1;
#pragma unroll
            for (int k = 0; k < 8; ++k) atomicAdd(&S_local[gi][cg * 8 + k], gen * v[k]);
            if (cg == 0) atomicAdd(&gz_local[gi], gen);
        }
    }
    __syncthreads();

    // ---- flush per-graph partials (33 atomics per graph spanned) ----
    int ngr = sgl - gfirst + 1; if (ngr > MAXG) ngr = MAXG;
    for (int i = t; i < ngr * 33; i += 1024) {
        int q = i / 33, c = i % 33;
        if (c < 32) atomicAdd(&Sg[(size_t)(gfirst + q) * 32 + c], S_local[q][c]);
        else atomicAdd(&gzg[gfirst + q], gz_local[q]);
    }
}

// ---------------- kernel 3: output head ----------------
__global__ __launch_bounds__(256) void k_out(const float* __restrict__ Sg,
                                             const float* __restrict__ gzg,
                                             const float* __restrict__ W_out,
                                             const float* __restrict__ b_out,
                                             float* __restrict__ out) {
    int g = blockIdx.x * blockDim.x + threadIdx.x;
    if (g >= N_GRAPHS) return;
    float zi = 1.f / (gzg[g] + SM_EPS);
    float acc = b_out[0];
#pragma unroll
    for (int k = 0; k < 32; ++k) acc += Sg[(size_t)g * 32 + k] * zi * W_out[k];
    out[g] = 1.f / (1.f + __expf(-acc));
}

extern "C" void kernel_launch(void* const* d_in, const int* in_sizes, int n_in,
                              void* d_out, int out_size, void* d_ws, size_t ws_size,
                              hipStream_t stream) {
    const float* x        = (const float*)d_in[0];
    const int*   ei       = (const int*)  d_in[1];
    const float* ea       = (const float*)d_in[2];
    const int*   batch    = (const int*)  d_in[3];
    const float* W        = (const float*)d_in[4];
    const float* att_src  = (const float*)d_in[5];
    const float* att_dst  = (const float*)d_in[6];
    const float* W_edge   = (const float*)d_in[7];
    const float* att_edge = (const float*)d_in[8];
    const float* bias     = (const float*)d_in[9];
    const float* W_gate   = (const float*)d_in[10];
    const float* b_gate   = (const float*)d_in[11];
    const float* W_out    = (const float*)d_in[12];
    const float* b_out    = (const float*)d_in[13];
    float* out = (float*)d_out;

    // workspace layout
    char* wsb = (char*)d_ws;
    uint2*    part_  = (uint2*)wsb;                                // NBIN*BIN_CAP uint2 = 15.5 MB
    __half2*  h2     = (__half2*)(part_ + (size_t)NBIN * BIN_CAP); // 16N half2 = 3.2 MB
    float*    a_src  = (float*)(h2 + (size_t)16 * N_NODES);        // N
    float*    a_dst  = a_src + N_NODES;                            // N
    // ---- zeroed region (contiguous: Sg, gzg, pcur) ----
    float*    Sg     = a_dst + N_NODES;                            // G*32
    float*    gzg    = Sg + (size_t)N_GRAPHS * 32;                 // G
    int*      pcur   = (int*)(gzg + N_GRAPHS);                     // NBIN

    size_t zero_bytes = ((size_t)N_GRAPHS * 33 + NBIN) * sizeof(float);
    hipMemsetAsync(Sg, 0, zero_bytes, stream);

    k_part_node<<<PART_BLOCKS, 512, 0, stream>>>(ei, ea, W_edge, att_edge, x, W, att_src,
                                                 att_dst, part_, pcur, h2, a_src, a_dst);
    k_asm_gather<<<NBIN, 1024, 0, stream>>>(part_, pcur, h2, a_src, a_dst, bias,
                                            W_gate, b_gate, batch, Sg, gzg);
    k_out<<<(N_GRAPHS + 255) / 256, 256, 0, stream>>>(Sg, gzg, W_out, b_out, out);
}

// Round 19
// 162.567 us; speedup vs baseline: 1.0796x; 1.0315x over previous
//
#include <hip/hip_runtime.h>
#include <hip/hip_fp16.h>
#include <math.h>

#define N_NODES 50000
#define N_EDGES 1600000
#define N_GRAPHS 512
#define HID 32
#define NEG_SLOPE 0.2f
#define SM_EPS 1e-16f
#define PAD 80          // max in-degree slots; dst~Poisson(32), P(deg>=80)*N ~ 5e-7
#define NBIN 511        // one bin per k_asm_gather block (ceil(50000/98))
#define BIN_W 98        // nodes per bin -> 98*80*4B = 31.4 KB LDS rows -> 2 blocks/CU
#define BIN_CAP 3800    // 3130 mean + ~12 sigma
#define EPT 10          // edges per thread in k_part_node
#define EPB 5120        // 512*EPT edges per block
#define PART_BLOCKS 313 // 313*5120 = 1,602,560 >= 1.6M edges; 313*160 = 50,080 nodes
#define MAXG 8          // max graphs spanned by one 98-node bin (typ. 2)

// ---------------- kernel 1: partition w/ LDS rank-sort + coalesced writeback, + node transform ----------------
__global__ __launch_bounds__(512) void k_part_node(const int* __restrict__ ei,
                                                   const float* __restrict__ ea,
                                                   const float* __restrict__ W_edge,
                                                   const float* __restrict__ att_edge,
                                                   const float* __restrict__ x,
                                                   const float* __restrict__ W,
                                                   const float* __restrict__ att_src,
                                                   const float* __restrict__ att_dst,
                                                   uint2* __restrict__ part,
                                                   int* __restrict__ pcur,
                                                   __half2* __restrict__ h2,
                                                   float* __restrict__ a_src,
                                                   float* __restrict__ a_dst) {
    __shared__ float sv[3];
    __shared__ float sW[12 * 32], sas[32], sad[32];
    __shared__ int lcnt[NBIN], lbase[NBIN], lcur[NBIN];
    __shared__ int sscan[512];
    __shared__ uint2 sbuf[EPB];          // 40 KB staging: entries sorted by bin
    int t = threadIdx.x;
    if (t < 3) {
        float v = 0.f;
        for (int j = 0; j < 32; ++j) v += W_edge[t * 32 + j] * att_edge[j];
        sv[t] = v;
    }
    for (int i = t; i < 12 * 32; i += 512) sW[i] = W[i];
    if (t < 32) { sas[t] = att_src[t]; sad[t] = att_dst[t]; }
    if (t < NBIN) lcnt[t] = 0;
    __syncthreads();

    // ---- phase A1: load edges, histogram with per-entry rank ----
    uint2 r[EPT];
    int bin[EPT], rank[EPT];
    int ebase = blockIdx.x * EPB + t;
#pragma unroll
    for (int i = 0; i < EPT; ++i) {
        int e = ebase + i * 512;
        if (e < N_EDGES) {
            int s = ei[e];
            int d = ei[N_EDGES + e];
            float aev = ea[e * 3 + 0] * sv[0] + ea[e * 3 + 1] * sv[1] + ea[e * 3 + 2] * sv[2];
            r[i] = make_uint2((unsigned)d | ((unsigned)s << 16), __float_as_uint(aev));
            bin[i] = d / BIN_W;
            rank[i] = atomicAdd(&lcnt[bin[i]], 1);
        } else {
            bin[i] = -1;
        }
    }
    __syncthreads();

    // ---- phase A2: exclusive scan of lcnt -> lbase; fetch global bases ----
    int v = (t < NBIN) ? lcnt[t] : 0;
    sscan[t] = v;
    __syncthreads();
    for (int ofs = 1; ofs < 512; ofs <<= 1) {
        int u = (t >= ofs) ? sscan[t - ofs] : 0;
        __syncthreads();
        sscan[t] += u;
        __syncthreads();
    }
    if (t < NBIN) {
        lbase[t] = sscan[t] - v;
        lcur[t] = atomicAdd(pcur + t, v);
    }
    __syncthreads();

    // ---- phase A3: scatter into LDS (sorted by bin) ----
#pragma unroll
    for (int i = 0; i < EPT; ++i)
        if (bin[i] >= 0) sbuf[lbase[bin[i]] + rank[i]] = r[i];
    __syncthreads();

    // ---- phase A4: coalesced writeback (consecutive lanes -> consecutive addresses in runs) ----
    int total = sscan[511];   // inclusive scan of all bins = #valid entries
    for (int i = t; i < total; i += 512) {
        uint2 e = sbuf[i];
        int bb = (int)(e.x & 0xFFFF) / BIN_W;
        int pos = lcur[bb] + (i - lbase[bb]);
        if (pos < BIN_CAP) part[(size_t)bb * BIN_CAP + pos] = e;
    }

    // ---- phase B: node transform, 160 nodes per block ----
    int n = blockIdx.x * 160 + t;
    if (t < 160 && n < N_NODES) {
        float xv[12];
#pragma unroll
        for (int j = 0; j < 12; ++j) xv[j] = x[n * 12 + j];
        float hv[32];
        float as = 0.f, ad = 0.f;
#pragma unroll
        for (int k = 0; k < 32; ++k) {
            float acc = 0.f;
#pragma unroll
            for (int j = 0; j < 12; ++j) acc += xv[j] * sW[j * 32 + k];
            hv[k] = acc;
            as += acc * sas[k];
            ad += acc * sad[k];
        }
        a_src[n] = as;
        a_dst[n] = ad;
        __half2 hp[16];
#pragma unroll
        for (int k = 0; k < 16; ++k) hp[k] = __floats2half2_rn(hv[2 * k], hv[2 * k + 1]);
        uint4* dst = (uint4*)(h2 + (size_t)n * 16);
        const uint4* srcp = (const uint4*)hp;
#pragma unroll
        for (int k = 0; k < 4; ++k) dst[k] = srcp[k];
    }
}

// ---------------- kernel 2: LDS assembly + gather + fused pooling (R13/R18 form — fastest measured) ----------------
__global__ __launch_bounds__(1024) void k_asm_gather(const uint2* __restrict__ part,
                                                     const int* __restrict__ pcur,
                                                     const __half2* __restrict__ h2,
                                                     const float* __restrict__ a_src,
                                                     const float* __restrict__ a_dst,
                                                     const float* __restrict__ bias,
                                                     const float* __restrict__ W_gate,
                                                     const float* __restrict__ b_gate,
                                                     const int* __restrict__ batch,
                                                     float* __restrict__ Sg,
                                                     float* __restrict__ gzg) {
    int b = blockIdx.x;
    int lo = b * BIN_W;
    if (lo >= N_NODES) return;
    int hi = lo + BIN_W; if (hi > N_NODES) hi = N_NODES;
    int nrow = hi - lo;
    __shared__ int lcur[BIN_W];
    __shared__ unsigned lbuck[BIN_W * PAD];   // 31.4 KB
    __shared__ float S_local[MAXG][32];
    __shared__ float gz_local[MAXG];
    __shared__ int sgf, sgl;
    int t = threadIdx.x;
    if (t < BIN_W) lcur[t] = 0;
    if (t < MAXG * 32) S_local[t >> 5][t & 31] = 0.f;
    if (t < MAXG) gz_local[t] = 0.f;
    if (t == 0) { sgf = batch[lo]; sgl = batch[hi - 1]; }
    __syncthreads();
    int gfirst = sgf;

    // ---- phase 1: assemble rows in LDS (own partition only, single read) ----
    int cnt = pcur[b]; if (cnt > BIN_CAP) cnt = BIN_CAP;
    const uint2* p = part + (size_t)b * BIN_CAP;
    for (int i = t; i < cnt; i += 1024) {
        uint2 r = p[i];
        int li = (int)(r.x & 0xFFFF) - lo;
        unsigned s = r.x >> 16;
        unsigned short hb = __half_as_ushort(__float2half_rn(__uint_as_float(r.y)));
        int pos = atomicAdd(&lcur[li], 1);
        if (pos < PAD) lbuck[li * PAD + pos] = s | ((unsigned)hb << 16);
    }
    __syncthreads();

    // ---- phase 2: wave-per-node gather (inline exp), pool into LDS ----
    int l = t & 63, wl = t >> 6;   // 16 waves
    int es = l >> 2;               // edge subgroup 0..15
    int cg = l & 3;                // channel group 0..3 (8 halves = one dwordx4)
    float bg0 = b_gate[0];

    for (int li = wl; li < nrow; li += 16) {
        int n = lo + li;
        int deg_full = lcur[li];
        int degc = deg_full < PAD ? deg_full : PAD;
        float adst_n = a_dst[n];
        const unsigned* row = lbuck + li * PAD;

        float c0 = 0.f, c1 = 0.f, c2 = 0.f, c3 = 0.f, c4 = 0.f, c5 = 0.f, c6 = 0.f, c7 = 0.f;
        float wsum = 0.f, aevsum = 0.f;
        int j = es;
        for (; j + 16 < degc; j += 32) {
            unsigned p0 = row[j], p1 = row[j + 16];
            int s0 = p0 & 0xFFFF, s1 = p1 & 0xFFFF;
            float aev0 = __half2float(__ushort_as_half((unsigned short)(p0 >> 16)));
            float aev1 = __half2float(__ushort_as_half((unsigned short)(p1 >> 16)));
            float as0 = a_src[s0], as1 = a_src[s1];
            const uint4 u0 = *(const uint4*)(h2 + (size_t)s0 * 16 + cg * 4);
            const uint4 u1 = *(const uint4*)(h2 + (size_t)s1 * 16 + cg * 4);
            float a0 = as0 + adst_n + aev0; a0 = a0 > 0.f ? a0 : NEG_SLOPE * a0;
            float a1 = as1 + adst_n + aev1; a1 = a1 > 0.f ? a1 : NEG_SLOPE * a1;
            float w0 = __expf(a0), w1 = __expf(a1);
            wsum += w0 + w1; aevsum += aev0 + aev1;
            float2 f;
            f = __half22float2(*(const __half2*)&u0.x); c0 += w0 * f.x; c1 += w0 * f.y;
            f = __half22float2(*(const __half2*)&u0.y); c2 += w0 * f.x; c3 += w0 * f.y;
            f = __half22float2(*(const __half2*)&u0.z); c4 += w0 * f.x; c5 += w0 * f.y;
            f = __half22float2(*(const __half2*)&u0.w); c6 += w0 * f.x; c7 += w0 * f.y;
            f = __half22float2(*(const __half2*)&u1.x); c0 += w1 * f.x; c1 += w1 * f.y;
            f = __half22float2(*(const __half2*)&u1.y); c2 += w1 * f.x; c3 += w1 * f.y;
            f = __half22float2(*(const __half2*)&u1.z); c4 += w1 * f.x; c5 += w1 * f.y;
            f = __half22float2(*(const __half2*)&u1.w); c6 += w1 * f.x; c7 += w1 * f.y;
        }
        if (j < degc) {
            unsigned p0 = row[j];
            int s0 = p0 & 0xFFFF;
            float aev0 = __half2float(__ushort_as_half((unsigned short)(p0 >> 16)));
            float a0 = a_src[s0] + adst_n + aev0; a0 = a0 > 0.f ? a0 : NEG_SLOPE * a0;
            float w0 = __expf(a0);
            const uint4 u0 = *(const uint4*)(h2 + (size_t)s0 * 16 + cg * 4);
            wsum += w0; aevsum += aev0;
            float2 f;
            f = __half22float2(*(const __half2*)&u0.x); c0 += w0 * f.x; c1 += w0 * f.y;
            f = __half22float2(*(const __half2*)&u0.y); c2 += w0 * f.x; c3 += w0 * f.y;
            f = __half22float2(*(const __half2*)&u0.z); c4 += w0 * f.x; c5 += w0 * f.y;
            f = __half22float2(*(const __half2*)&u0.w); c6 += w0 * f.x; c7 += w0 * f.y;
        }

#pragma unroll
        for (int m = 4; m <= 32; m <<= 1) {
            c0 += __shfl_xor(c0, m); c1 += __shfl_xor(c1, m);
            c2 += __shfl_xor(c2, m); c3 += __shfl_xor(c3, m);
            c4 += __shfl_xor(c4, m); c5 += __shfl_xor(c5, m);
            c6 += __shfl_xor(c6, m); c7 += __shfl_xor(c7, m);
            wsum += __shfl_xor(wsum, m); aevsum += __shfl_xor(aevsum, m);
        }

        float dgm = deg_full > 1 ? (float)deg_full : 1.f;
        float al = a_src[n] + adst_n + aevsum / dgm;
        al = al > 0.f ? al : NEG_SLOPE * al;
        float el = __expf(al);
        float zi = 1.f / (wsum + el + SM_EPS);

        if (es == 0) {          // lanes 0..3, 8 channels each
            const uint4 un = *(const uint4*)(h2 + (size_t)n * 16 + cg * 4);
            float hn[8];
            float2 f;
            f = __half22float2(*(const __half2*)&un.x); hn[0] = f.x; hn[1] = f.y;
            f = __half22float2(*(const __half2*)&un.y); hn[2] = f.x; hn[3] = f.y;
            f = __half22float2(*(const __half2*)&un.z); hn[4] = f.x; hn[5] = f.y;
            f = __half22float2(*(const __half2*)&un.w); hn[6] = f.x; hn[7] = f.y;
            const float4 bva = *(const float4*)(bias + cg * 8);
            const float4 bvb = *(const float4*)(bias + cg * 8 + 4);
            float v[8];
            v[0] = (c0 + el * hn[0]) * zi + bva.x;
            v[1] = (c1 + el * hn[1]) * zi + bva.y;
            v[2] = (c2 + el * hn[2]) * zi + bva.z;
            v[3] = (c3 + el * hn[3]) * zi + bva.w;
            v[4] = (c4 + el * hn[4]) * zi + bvb.x;
            v[5] = (c5 + el * hn[5]) * zi + bvb.y;
            v[6] = (c6 + el * hn[6]) * zi + bvb.z;
            v[7] = (c7 + el * hn[7]) * zi + bvb.w;
#pragma unroll
            for (int k = 0; k < 8; ++k) v[k] = v[k] > 0.f ? v[k] : 0.f;   // relu
            const float4 wga = *(const float4*)(W_gate + cg * 8);
            const float4 wgb = *(const float4*)(W_gate + cg * 8 + 4);
            float g = v[0] * wga.x + v[1] * wga.y + v[2] * wga.z + v[3] * wga.w
                    + v[4] * wgb.x + v[5] * wgb.y + v[6] * wgb.z + v[7] * wgb.w;
            g += __shfl_xor(g, 1);
            g += __shfl_xor(g, 2);      // all 4 lanes hold the full gate dot
            float gen = __expf(g + bg0);
            int gi = batch[n] - gfirst; gi = gi < MAXG - 1 ? gi : MAXG - 1;
#pragma unroll
            for (int k = 0; k < 8; ++k) atomicAdd(&S_local[gi][cg * 8 + k], gen * v[k]);
            if (cg == 0) atomicAdd(&gz_local[gi], gen);
        }
    }
    __syncthreads();

    // ---- flush per-graph partials (33 atomics per graph spanned) ----
    int ngr = sgl - gfirst + 1; if (ngr > MAXG) ngr = MAXG;
    for (int i = t; i < ngr * 33; i += 1024) {
        int q = i / 33, c = i % 33;
        if (c < 32) atomicAdd(&Sg[(size_t)(gfirst + q) * 32 + c], S_local[q][c]);
        else atomicAdd(&gzg[gfirst + q], gz_local[q]);
    }
}

// ---------------- kernel 3: output head ----------------
__global__ __launch_bounds__(256) void k_out(const float* __restrict__ Sg,
                                             const float* __restrict__ gzg,
                                             const float* __restrict__ W_out,
                                             const float* __restrict__ b_out,
                                             float* __restrict__ out) {
    int g = blockIdx.x * blockDim.x + threadIdx.x;
    if (g >= N_GRAPHS) return;
    float zi = 1.f / (gzg[g] + SM_EPS);
    float acc = b_out[0];
#pragma unroll
    for (int k = 0; k < 32; ++k) acc += Sg[(size_t)g * 32 + k] * zi * W_out[k];
    out[g] = 1.f / (1.f + __expf(-acc));
}

extern "C" void kernel_launch(void* const* d_in, const int* in_sizes, int n_in,
                              void* d_out, int out_size, void* d_ws, size_t ws_size,
                              hipStream_t stream) {
    const float* x        = (const float*)d_in[0];
    const int*   ei       = (const int*)  d_in[1];
    const float* ea       = (const float*)d_in[2];
    const int*   batch    = (const int*)  d_in[3];
    const float* W        = (const float*)d_in[4];
    const float* att_src  = (const float*)d_in[5];
    const float* att_dst  = (const float*)d_in[6];
    const float* W_edge   = (const float*)d_in[7];
    const float* att_edge = (const float*)d_in[8];
    const float* bias     = (const float*)d_in[9];
    const float* W_gate   = (const float*)d_in[10];
    const float* b_gate   = (const float*)d_in[11];
    const float* W_out    = (const float*)d_in[12];
    const float* b_out    = (const float*)d_in[13];
    float* out = (float*)d_out;

    // workspace layout
    char* wsb = (char*)d_ws;
    uint2*    part_  = (uint2*)wsb;                                // NBIN*BIN_CAP uint2 = 15.5 MB
    __half2*  h2     = (__half2*)(part_ + (size_t)NBIN * BIN_CAP); // 16N half2 = 3.2 MB
    float*    a_src  = (float*)(h2 + (size_t)16 * N_NODES);        // N
    float*    a_dst  = a_src + N_NODES;                            // N
    // ---- zeroed region (contiguous: Sg, gzg, pcur) ----
    float*    Sg     = a_dst + N_NODES;                            // G*32
    float*    gzg    = Sg + (size_t)N_GRAPHS * 32;                 // G
    int*      pcur   = (int*)(gzg + N_GRAPHS);                     // NBIN

    size_t zero_bytes = ((size_t)N_GRAPHS * 33 + NBIN) * sizeof(float);
    hipMemsetAsync(Sg, 0, zero_bytes, stream);

    k_part_node<<<PART_BLOCKS, 512, 0, stream>>>(ei, ea, W_edge, att_edge, x, W, att_src,
                                                 att_dst, part_, pcur, h2, a_src, a_dst);
    k_asm_gather<<<NBIN, 1024, 0, stream>>>(part_, pcur, h2, a_src, a_dst, bias,
                                            W_gate, b_gate, batch, Sg, gzg);
    k_out<<<(N_GRAPHS + 255) / 256, 256, 0, stream>>>(Sg, gzg, W_out, b_out, out);
}

// Round 20
// 149.612 us; speedup vs baseline: 1.1731x; 1.0866x over previous
//
#include <hip/hip_runtime.h>
#include <hip/hip_fp16.h>
#include <math.h>

#define N_NODES 50000
#define N_EDGES 1600000
#define N_GRAPHS 512
#define HID 32
#define NEG_SLOPE 0.2f
#define SM_EPS 1e-16f
#define PAD 80          // max in-degree slots; dst~Poisson(32), P(deg>=80)*N ~ 5e-7
#define NBIN 511        // one bin per k_asm_gather block (ceil(50000/98))
#define BIN_W 98        // nodes per bin -> 98*80*4B = 31.4 KB LDS rows -> 2 blocks/CU
#define BIN_CAP 3800    // 3130 mean + ~12 sigma
#define EPT 10          // edges per thread in k_part_node
#define EPB 5120        // 512*EPT edges per block
#define PART_BLOCKS 313 // 313*5120 = 1,602,560 >= 1.6M edges; 313*160 = 50,080 nodes
#define MAXG 8          // max graphs spanned by one 98-node bin (typ. 2)

// ---------------- kernel 1: partition w/ LDS rank-sort + coalesced writeback, + node transform ----------------
__global__ __launch_bounds__(512) void k_part_node(const int* __restrict__ ei,
                                                   const float* __restrict__ ea,
                                                   const float* __restrict__ W_edge,
                                                   const float* __restrict__ att_edge,
                                                   const float* __restrict__ x,
                                                   const float* __restrict__ W,
                                                   const float* __restrict__ att_src,
                                                   const float* __restrict__ att_dst,
                                                   uint2* __restrict__ part,
                                                   int* __restrict__ pcur,
                                                   __half2* __restrict__ h2,
                                                   float* __restrict__ a_src,
                                                   float* __restrict__ a_dst) {
    __shared__ float sv[3];
    __shared__ float sW[12 * 32], sas[32], sad[32];
    __shared__ int lcnt[NBIN], lbase[NBIN], lcur[NBIN];
    __shared__ int sscan[512];
    __shared__ uint2 sbuf[EPB];          // 40 KB staging: entries sorted by bin
    int t = threadIdx.x;
    if (t < 3) {
        float v = 0.f;
        for (int j = 0; j < 32; ++j) v += W_edge[t * 32 + j] * att_edge[j];
        sv[t] = v;
    }
    for (int i = t; i < 12 * 32; i += 512) sW[i] = W[i];
    if (t < 32) { sas[t] = att_src[t]; sad[t] = att_dst[t]; }
    if (t < NBIN) lcnt[t] = 0;
    __syncthreads();

    // ---- phase A1: load edges, histogram with per-entry rank ----
    uint2 r[EPT];
    int bin[EPT], rank[EPT];
    int ebase = blockIdx.x * EPB + t;
#pragma unroll
    for (int i = 0; i < EPT; ++i) {
        int e = ebase + i * 512;
        if (e < N_EDGES) {
            int s = ei[e];
            int d = ei[N_EDGES + e];
            float aev = ea[e * 3 + 0] * sv[0] + ea[e * 3 + 1] * sv[1] + ea[e * 3 + 2] * sv[2];
            r[i] = make_uint2((unsigned)d | ((unsigned)s << 16), __float_as_uint(aev));
            bin[i] = d / BIN_W;
            rank[i] = atomicAdd(&lcnt[bin[i]], 1);
        } else {
            bin[i] = -1;
        }
    }
    __syncthreads();

    // ---- phase A2: exclusive scan of lcnt -> lbase; fetch global bases ----
    int v = (t < NBIN) ? lcnt[t] : 0;
    sscan[t] = v;
    __syncthreads();
    for (int ofs = 1; ofs < 512; ofs <<= 1) {
        int u = (t >= ofs) ? sscan[t - ofs] : 0;
        __syncthreads();
        sscan[t] += u;
        __syncthreads();
    }
    if (t < NBIN) {
        lbase[t] = sscan[t] - v;
        lcur[t] = atomicAdd(pcur + t, v);
    }
    __syncthreads();

    // ---- phase A3: scatter into LDS (sorted by bin) ----
#pragma unroll
    for (int i = 0; i < EPT; ++i)
        if (bin[i] >= 0) sbuf[lbase[bin[i]] + rank[i]] = r[i];
    __syncthreads();

    // ---- phase A4: coalesced writeback ----
    int total = sscan[511];
    for (int i = t; i < total; i += 512) {
        uint2 e = sbuf[i];
        int bb = (int)(e.x & 0xFFFF) / BIN_W;
        int pos = lcur[bb] + (i - lbase[bb]);
        if (pos < BIN_CAP) part[(size_t)bb * BIN_CAP + pos] = e;
    }

    // ---- phase B: node transform, 160 nodes per block ----
    int n = blockIdx.x * 160 + t;
    if (t < 160 && n < N_NODES) {
        float xv[12];
#pragma unroll
        for (int j = 0; j < 12; ++j) xv[j] = x[n * 12 + j];
        float hv[32];
        float as = 0.f, ad = 0.f;
#pragma unroll
        for (int k = 0; k < 32; ++k) {
            float acc = 0.f;
#pragma unroll
            for (int j = 0; j < 12; ++j) acc += xv[j] * sW[j * 32 + k];
            hv[k] = acc;
            as += acc * sas[k];
            ad += acc * sad[k];
        }
        a_src[n] = as;
        a_dst[n] = ad;
        __half2 hp[16];
#pragma unroll
        for (int k = 0; k < 16; ++k) hp[k] = __floats2half2_rn(hv[2 * k], hv[2 * k + 1]);
        uint4* dst = (uint4*)(h2 + (size_t)n * 16);
        const uint4* srcp = (const uint4*)hp;
#pragma unroll
        for (int k = 0; k < 4; ++k) dst[k] = srcp[k];
    }
}

// ---------------- kernel 2: LDS assembly + gather + fused pooling; phase-2 lane map es8/cg8 ----------------
// es8/cg8: 18 shuffles/row (vs es16's 40) while keeping 8 B vectorized h2 loads.
__global__ __launch_bounds__(1024) void k_asm_gather(const uint2* __restrict__ part,
                                                     const int* __restrict__ pcur,
                                                     const __half2* __restrict__ h2,
                                                     const float* __restrict__ a_src,
                                                     const float* __restrict__ a_dst,
                                                     const float* __restrict__ bias,
                                                     const float* __restrict__ W_gate,
                                                     const float* __restrict__ b_gate,
                                                     const int* __restrict__ batch,
                                                     float* __restrict__ Sg,
                                                     float* __restrict__ gzg) {
    int b = blockIdx.x;
    int lo = b * BIN_W;
    if (lo >= N_NODES) return;
    int hi = lo + BIN_W; if (hi > N_NODES) hi = N_NODES;
    int nrow = hi - lo;
    __shared__ int lcur[BIN_W];
    __shared__ unsigned lbuck[BIN_W * PAD];   // 31.4 KB
    __shared__ float S_local[MAXG][32];
    __shared__ float gz_local[MAXG];
    __shared__ int sgf, sgl;
    int t = threadIdx.x;
    if (t < BIN_W) lcur[t] = 0;
    if (t < MAXG * 32) S_local[t >> 5][t & 31] = 0.f;
    if (t < MAXG) gz_local[t] = 0.f;
    if (t == 0) { sgf = batch[lo]; sgl = batch[hi - 1]; }
    __syncthreads();
    int gfirst = sgf;

    // ---- phase 1: assemble rows in LDS (own partition only, single read) ----
    int cnt = pcur[b]; if (cnt > BIN_CAP) cnt = BIN_CAP;
    const uint2* p = part + (size_t)b * BIN_CAP;
    for (int i = t; i < cnt; i += 1024) {
        uint2 r = p[i];
        int li = (int)(r.x & 0xFFFF) - lo;
        unsigned s = r.x >> 16;
        unsigned short hb = __half_as_ushort(__float2half_rn(__uint_as_float(r.y)));
        int pos = atomicAdd(&lcur[li], 1);
        if (pos < PAD) lbuck[li * PAD + pos] = s | ((unsigned)hb << 16);
    }
    __syncthreads();

    // ---- phase 2: wave-per-node gather; es = l>>3 (0..7), cg = l&7 (4 halves each, uint2) ----
    int l = t & 63, wl = t >> 6;   // 16 waves
    int es = l >> 3;               // edge subgroup 0..7
    int cg = l & 7;                // channel group 0..7 (4 halves = one dwordx2)
    float bg0 = b_gate[0];

    for (int li = wl; li < nrow; li += 16) {
        int n = lo + li;
        int deg_full = lcur[li];
        int degc = deg_full < PAD ? deg_full : PAD;
        float adst_n = a_dst[n];
        const unsigned* row = lbuck + li * PAD;

        float c0 = 0.f, c1 = 0.f, c2 = 0.f, c3 = 0.f;
        float wsum = 0.f, aevsum = 0.f;
        int j = es;
        for (; j + 8 < degc; j += 16) {
            unsigned p0 = row[j], p1 = row[j + 8];
            int s0 = p0 & 0xFFFF, s1 = p1 & 0xFFFF;
            float aev0 = __half2float(__ushort_as_half((unsigned short)(p0 >> 16)));
            float aev1 = __half2float(__ushort_as_half((unsigned short)(p1 >> 16)));
            float as0 = a_src[s0], as1 = a_src[s1];
            const uint2 u0 = *(const uint2*)(h2 + (size_t)s0 * 16 + cg * 2);
            const uint2 u1 = *(const uint2*)(h2 + (size_t)s1 * 16 + cg * 2);
            float a0 = as0 + adst_n + aev0; a0 = a0 > 0.f ? a0 : NEG_SLOPE * a0;
            float a1 = as1 + adst_n + aev1; a1 = a1 > 0.f ? a1 : NEG_SLOPE * a1;
            float w0 = __expf(a0), w1 = __expf(a1);
            wsum += w0 + w1; aevsum += aev0 + aev1;
            float2 f;
            f = __half22float2(*(const __half2*)&u0.x); c0 += w0 * f.x; c1 += w0 * f.y;
            f = __half22float2(*(const __half2*)&u0.y); c2 += w0 * f.x; c3 += w0 * f.y;
            f = __half22float2(*(const __half2*)&u1.x); c0 += w1 * f.x; c1 += w1 * f.y;
            f = __half22float2(*(const __half2*)&u1.y); c2 += w1 * f.x; c3 += w1 * f.y;
        }
        if (j < degc) {
            unsigned p0 = row[j];
            int s0 = p0 & 0xFFFF;
            float aev0 = __half2float(__ushort_as_half((unsigned short)(p0 >> 16)));
            float a0 = a_src[s0] + adst_n + aev0; a0 = a0 > 0.f ? a0 : NEG_SLOPE * a0;
            float w0 = __expf(a0);
            const uint2 u0 = *(const uint2*)(h2 + (size_t)s0 * 16 + cg * 2);
            wsum += w0; aevsum += aev0;
            float2 f;
            f = __half22float2(*(const __half2*)&u0.x); c0 += w0 * f.x; c1 += w0 * f.y;
            f = __half22float2(*(const __half2*)&u0.y); c2 += w0 * f.x; c3 += w0 * f.y;
        }

        // reduce over es (lanes sharing cg): xor 8, 16, 32 — 18 shfl total
#pragma unroll
        for (int m = 8; m <= 32; m <<= 1) {
            c0 += __shfl_xor(c0, m); c1 += __shfl_xor(c1, m);
            c2 += __shfl_xor(c2, m); c3 += __shfl_xor(c3, m);
            wsum += __shfl_xor(wsum, m); aevsum += __shfl_xor(aevsum, m);
        }

        float dgm = deg_full > 1 ? (float)deg_full : 1.f;
        float al = a_src[n] + adst_n + aevsum / dgm;
        al = al > 0.f ? al : NEG_SLOPE * al;
        float el = __expf(al);
        float zi = 1.f / (wsum + el + SM_EPS);

        if (es == 0) {          // lanes 0..7, 4 channels each
            const uint2 un = *(const uint2*)(h2 + (size_t)n * 16 + cg * 2);
            float hn[4];
            float2 f;
            f = __half22float2(*(const __half2*)&un.x); hn[0] = f.x; hn[1] = f.y;
            f = __half22float2(*(const __half2*)&un.y); hn[2] = f.x; hn[3] = f.y;
            const float4 bv = *(const float4*)(bias + cg * 4);
            float v[4];
            v[0] = (c0 + el * hn[0]) * zi + bv.x;
            v[1] = (c1 + el * hn[1]) * zi + bv.y;
            v[2] = (c2 + el * hn[2]) * zi + bv.z;
            v[3] = (c3 + el * hn[3]) * zi + bv.w;
#pragma unroll
            for (int k = 0; k < 4; ++k) v[k] = v[k] > 0.f ? v[k] : 0.f;   // relu
            const float4 wg = *(const float4*)(W_gate + cg * 4);
            float g = v[0] * wg.x + v[1] * wg.y + v[2] * wg.z + v[3] * wg.w;
            g += __shfl_xor(g, 1);
            g += __shfl_xor(g, 2);
            g += __shfl_xor(g, 4);      // all 8 lanes hold the full gate dot
            float gen = __expf(g + bg0);
            int gi = batch[n] - gfirst; gi = gi < MAXG - 1 ? gi : MAXG - 1;
#pragma unroll
            for (int k = 0; k < 4; ++k) atomicAdd(&S_local[gi][cg * 4 + k], gen * v[k]);
            if (cg == 0) atomicAdd(&gz_local[gi], gen);
        }
    }
    __syncthreads();

    // ---- flush per-graph partials (33 atomics per graph spanned) ----
    int ngr = sgl - gfirst + 1; if (ngr > MAXG) ngr = MAXG;
    for (int i = t; i < ngr * 33; i += 1024) {
        int q = i / 33, c = i % 33;
        if (c < 32) atomicAdd(&Sg[(size_t)(gfirst + q) * 32 + c], S_local[q][c]);
        else atomicAdd(&gzg[gfirst + q], gz_local[q]);
    }
}

// ---------------- kernel 3: output head ----------------
__global__ __launch_bounds__(256) void k_out(const float* __restrict__ Sg,
                                             const float* __restrict__ gzg,
                                             const float* __restrict__ W_out,
                                             const float* __restrict__ b_out,
                                             float* __restrict__ out) {
    int g = blockIdx.x * blockDim.x + threadIdx.x;
    if (g >= N_GRAPHS) return;
    float zi = 1.f / (gzg[g] + SM_EPS);
    float acc = b_out[0];
#pragma unroll
    for (int k = 0; k < 32; ++k) acc += Sg[(size_t)g * 32 + k] * zi * W_out[k];
    out[g] = 1.f / (1.f + __expf(-acc));
}

extern "C" void kernel_launch(void* const* d_in, const int* in_sizes, int n_in,
                              void* d_out, int out_size, void* d_ws, size_t ws_size,
                              hipStream_t stream) {
    const float* x        = (const float*)d_in[0];
    const int*   ei       = (const int*)  d_in[1];
    const float* ea       = (const float*)d_in[2];
    const int*   batch    = (const int*)  d_in[3];
    const float* W        = (const float*)d_in[4];
    const float* att_src  = (const float*)d_in[5];
    const float* att_dst  = (const float*)d_in[6];
    const float* W_edge   = (const float*)d_in[7];
    const float* att_edge = (const float*)d_in[8];
    const float* bias     = (const float*)d_in[9];
    const float* W_gate   = (const float*)d_in[10];
    const float* b_gate   = (const float*)d_in[11];
    const float* W_out    = (const float*)d_in[12];
    const float* b_out    = (const float*)d_in[13];
    float* out = (float*)d_out;

    // workspace layout
    char* wsb = (char*)d_ws;
    uint2*    part_  = (uint2*)wsb;                                // NBIN*BIN_CAP uint2 = 15.5 MB
    __half2*  h2     = (__half2*)(part_ + (size_t)NBIN * BIN_CAP); // 16N half2 = 3.2 MB
    float*    a_src  = (float*)(h2 + (size_t)16 * N_NODES);        // N
    float*    a_dst  = a_src + N_NODES;                            // N
    // ---- zeroed region (contiguous: Sg, gzg, pcur) ----
    float*    Sg     = a_dst + N_NODES;                            // G*32
    float*    gzg    = Sg + (size_t)N_GRAPHS * 32;                 // G
    int*      pcur   = (int*)(gzg + N_GRAPHS);                     // NBIN

    size_t zero_bytes = ((size_t)N_GRAPHS * 33 + NBIN) * sizeof(float);
    hipMemsetAsync(Sg, 0, zero_bytes, stream);

    k_part_node<<<PART_BLOCKS, 512, 0, stream>>>(ei, ea, W_edge, att_edge, x, W, att_src,
                                                 att_dst, part_, pcur, h2, a_src, a_dst);
    k_asm_gather<<<NBIN, 1024, 0, stream>>>(part_, pcur, h2, a_src, a_dst, bias,
                                            W_gate, b_gate, batch, Sg, gzg);
    k_out<<<(N_GRAPHS + 255) / 256, 256, 0, stream>>>(Sg, gzg, W_out, b_out, out);
}